// Round 8
// baseline (984.538 us; speedup 1.0000x reference)
//
#include <hip/hip_runtime.h>
#include <hip/hip_bf16.h>

#define NCODES 1024
#define DIMS   256
#define HWSZ   4096
#define NPOS   65536

// ---------------- shared helpers ----------------
__device__ __forceinline__ unsigned short f2bf_rne(float f) {
    unsigned int x = __float_as_uint(f);
    unsigned int r = x + 0x7fffu + ((x >> 16) & 1u);
    return (unsigned short)(r >> 16);
}
__device__ __forceinline__ float bf2f(unsigned short h) {
    return __uint_as_float(((unsigned int)h) << 16);
}
__device__ __forceinline__ void gl_lds16(const void* g, void* l) {
    __builtin_amdgcn_global_load_lds(
        (const __attribute__((address_space(1))) unsigned int*)g,
        (__attribute__((address_space(3))) unsigned int*)l, 16, 0, 0);
}

typedef short bf16x8v __attribute__((ext_vector_type(8)));
typedef float f32x4  __attribute__((ext_vector_type(4)));

// ================= NEW MFMA PATH ws layout (float words) =================
#define WM_CNT   0
#define WM_PART  64        // 512 block partials (pass3)
#define WM_B     1024      // 1024 exact ||e||^2
#define WM_A     2048      // 65536 exact ||z||^2
#define WM_IDX   67584     // 65536 int
#define WM_LIST  133120    // 65536 int
#define WM_BM    198656    // B bf16 frag-tiled: 1024x768 = 786432 bf16 = 393216 words
#define WM_AM    591872    // A bf16 frag-tiled: 65536x512 = 16777216 words
#define WM_END_BYTES 69476352ull
#define THRESH 2.5e-4f

// ---------- prep_cb_m: exact b_k + B_mem bf16 frag-tiled [kc][ci][cg][q][c16][8] ----------
__global__ void prep_cb_m(const float* __restrict__ cb, float* __restrict__ ws) {
#pragma clang fp contract(off)
    int k = blockIdx.x * 256 + threadIdx.x;   // 0..1023
    if (k == 0) ((int*)ws)[WM_CNT] = 0;
    float s = 0.0f;
    for (int c = 0; c < DIMS; ++c) {
        float v = cb[k * DIMS + c];
        float p = v * v;
        s = s + p;
    }
    ws[WM_B + k] = s;

    unsigned short* Bm = (unsigned short*)(ws + WM_BM);
    const int kc = k >> 8, cg = (k >> 4) & 15, c16 = k & 15;
    for (int ci = 0; ci < 24; ++ci) {
        const int base = (ci < 8 ? ci : (ci < 16 ? ci - 8 : ci - 16)) * 32;
        const bool lo = (ci >= 8 && ci < 16);
        for (int q = 0; q < 4; ++q) {
            union { unsigned short u[8]; uint4 v4; } pk;
#pragma unroll
            for (int j = 0; j < 8; ++j) {
                float v = cb[k * DIMS + base + q * 8 + j];
                unsigned short h = f2bf_rne(v);
                if (lo) h = f2bf_rne(v - bf2f(h));
                pk.u[j] = h;
            }
            size_t off = ((size_t)(((kc * 24 + ci) * 16 + cg) * 4 + q)) * 128 + c16 * 8;
            *(uint4*)(Bm + off) = pk.v4;
        }
    }
}

// ---------- prep_a_m: exact a_n (identical math to verified a_kernel) ----------
__global__ void prep_a_m(const float* __restrict__ z, float* __restrict__ ws) {
#pragma clang fp contract(off)
    int n = blockIdx.x * blockDim.x + threadIdx.x;
    int b = n >> 12;
    int hw = n & 4095;
    const float* zp = z + (size_t)b * DIMS * HWSZ + hw;
    float s = 0.0f;
    for (int c = 0; c < DIMS; ++c) {
        float v = zp[(size_t)c * HWSZ];
        float p = v * v;
        s = s + p;
    }
    ws[WM_A + n] = s;
}

// ---------- prep_zsplit: z -> A_mem frag-tiled [tile][kp16][g*4+q][p16][8] ----------
__global__ __launch_bounds__(256)
void prep_zsplit(const float* __restrict__ z, float* __restrict__ ws) {
    __shared__ float lz[128 * 64];   // 32 KB half-tile [c_local][p]
    unsigned short* Am = (unsigned short*)(ws + WM_AM);
    const int t = threadIdx.x;
    const int tile = blockIdx.x;            // 0..1023
    const int n0 = tile * 64;
    const int b = n0 >> 12, hw0 = n0 & 4095;
    const size_t zbase = (size_t)b * DIMS * HWSZ + hw0;
    const int p = t & 63, grp = t >> 6;
    unsigned short* At = Am + (size_t)tile * 32768;   // 65536 B = 32768 bf16

    for (int half = 0; half < 2; ++half) {
        const int coff = half * 128;
        __syncthreads();
        for (int rep = 0; rep < 32; ++rep) {
            int cl = rep * 4 + grp;
            lz[cl * 64 + p] = z[zbase + (size_t)(coff + cl) * HWSZ + p];
        }
        __syncthreads();
        for (int run = 0; run < 4; ++run) {
            const int c0l = grp * 32 + run * 8;
            union { unsigned short u[8]; uint4 v4; } hh, ll;
#pragma unroll
            for (int j = 0; j < 8; ++j) {
                float v = lz[(c0l + j) * 64 + p];
                unsigned short h = f2bf_rne(v);
                hh.u[j] = h;
                ll.u[j] = f2bf_rne(v - bf2f(h));
            }
            const int kp = (coff >> 5) + grp;     // 0..3 / 4..7
            const size_t byteH = (size_t)kp * 4096 +
                                 (size_t)((p >> 4) * 4 + run) * 256 + (p & 15) * 16;
            *(uint4*)((char*)At + byteH)         = hh.v4;
            *(uint4*)((char*)At + byteH + 32768) = ll.v4;   // kp+8 (zl)
        }
    }
}

// ---------- vq_mfma_k: 64 pos x 1024 codes per block, K=768 split-contraction ----------
__global__ __launch_bounds__(256, 4)
void vq_mfma_k(const float* __restrict__ ws_ro, float* __restrict__ ws) {
    __shared__ char Al[4096];
    __shared__ char Bl[16384];
    __shared__ float rd1[256], rd2[256];
    __shared__ int   ri[256];

    const int t = threadIdx.x, w = t >> 6, lane = t & 63;
    const int rg = lane >> 4, cl = lane & 15;
    const int tile = blockIdx.x, n0 = tile * 64;

    const unsigned short* Am = (const unsigned short*)(ws_ro + WM_AM);
    const unsigned short* Bm = (const unsigned short*)(ws_ro + WM_BM);
    const float* bsum = ws_ro + WM_B;
    const char* Atile = (const char*)(Am + (size_t)tile * 32768);

    rd1[t] = 1e30f; rd2[t] = 1e30f; ri[t] = 0;

    for (int kc = 0; kc < 4; ++kc) {
        f32x4 acc[4][4];
#pragma unroll
        for (int g = 0; g < 4; ++g)
#pragma unroll
            for (int bb = 0; bb < 4; ++bb)
#pragma unroll
                for (int r = 0; r < 4; ++r) acc[g][bb][r] = 0.0f;

        for (int ci = 0; ci < 24; ++ci) {
            __syncthreads();
            const int kp = (ci < 8) ? ci : ci - 8;
            gl_lds16(Atile + (size_t)kp * 4096 + t * 16, Al + (t & ~63) * 16);
            const char* Bci = (const char*)Bm + (size_t)(kc * 24 + ci) * 16384;
#pragma unroll
            for (int i = 0; i < 4; ++i)
                gl_lds16(Bci + (size_t)(i * 256 + t) * 16,
                         Bl + i * 4096 + (t & ~63) * 16);
            __syncthreads();

            bf16x8v af[4], bfv[4];
#pragma unroll
            for (int g = 0; g < 4; ++g)
                af[g] = *(const bf16x8v*)(Al + (g * 4 + rg) * 256 + cl * 16);
#pragma unroll
            for (int bb = 0; bb < 4; ++bb)
                bfv[bb] = *(const bf16x8v*)(Bl + ((w * 4 + bb) * 4 + rg) * 256 + cl * 16);
#pragma unroll
            for (int g = 0; g < 4; ++g)
#pragma unroll
                for (int bb = 0; bb < 4; ++bb)
                    acc[g][bb] = __builtin_amdgcn_mfma_f32_16x16x32_bf16(
                        af[g], bfv[bb], acc[g][bb], 0, 0, 0);
        }

        // per-kc argmin epilogue (approx s = b_k - 2*dot; a_n drops out of argmin)
        const int cwbase = kc * 256 + w * 64;
        float bs[4];
#pragma unroll
        for (int bb = 0; bb < 4; ++bb) bs[bb] = bsum[cwbase + bb * 16 + cl];

#pragma unroll
        for (int g = 0; g < 4; ++g) {
#pragma unroll
            for (int r = 0; r < 4; ++r) {
                float d1 = 1e30f, d2 = 1e30f; int i1 = 0;
#pragma unroll
                for (int bb = 0; bb < 4; ++bb) {
                    float s = fmaf(-2.0f, acc[g][bb][r], bs[bb]);
                    int kk = cwbase + bb * 16 + cl;
                    if (s < d1) { d2 = d1; d1 = s; i1 = kk; }
                    else if (s < d2) d2 = s;
                }
#pragma unroll
                for (int off = 1; off < 16; off <<= 1) {
                    float o1 = __shfl_xor(d1, off);
                    float o2 = __shfl_xor(d2, off);
                    int   oi = __shfl_xor(i1, off);
                    float nm = fminf(fmaxf(d1, o1), fminf(d2, o2));
                    bool take = (o1 < d1) || (o1 == d1 && oi < i1);
                    d1 = take ? o1 : d1; i1 = take ? oi : i1; d2 = nm;
                }
                if (cl == 0) {
                    int slot = w * 64 + g * 16 + rg * 4 + r;
                    float o1 = rd1[slot], o2 = rd2[slot];
                    if (d1 < o1) { ri[slot] = i1; rd1[slot] = d1; rd2[slot] = fminf(o1, d2); }
                    else          rd2[slot] = fminf(o2, d1);
                }
            }
        }
    }

    __syncthreads();
    if (t < 64) {
        float d1 = rd1[t], d2 = rd2[t]; int i1 = ri[t];
#pragma unroll
        for (int ww = 1; ww < 4; ++ww) {
            float o1 = rd1[ww * 64 + t], o2 = rd2[ww * 64 + t];
            int   oi = ri[ww * 64 + t];
            if (o1 < d1) { d2 = fminf(d1, o2); d1 = o1; i1 = oi; }
            else          d2 = fminf(d2, o1);
        }
        ((int*)ws)[WM_IDX + n0 + t] = i1;
        if (d2 - d1 < THRESH) {
            int slot = atomicAdd((int*)ws + WM_CNT, 1);
            ((int*)ws)[WM_LIST + slot] = n0 + t;
        }
    }
}

// ---------- rescue: exact f32 re-solve of flagged rows (bit-replicates reference) ----------
__global__ void rescue_k(const float* __restrict__ z, const float* __restrict__ cb,
                         float* __restrict__ ws) {
#pragma clang fp contract(off)
    const int t = threadIdx.x, lane = t & 63;
    const int wslot = blockIdx.x * 4 + (t >> 6);
    const int cnt = ((const int*)ws)[WM_CNT];
    for (int i = wslot; i < cnt; i += 1024) {
        const int row = ((const int*)ws)[WM_LIST + i];
        const int b = row >> 12, hw = row & 4095;
        const float* zp = z + (size_t)b * DIMS * HWSZ + hw;
        const float a = ws[WM_A + row];
        float d1 = 1e30f; int i1 = 0;
        for (int j = 0; j < 16; ++j) {
            const int kk = lane * 16 + j;
            const float* cr = cb + (size_t)kk * DIMS;
            float acc = 0.0f;
            for (int c4 = 0; c4 < 64; ++c4) {
                float4 cv = *(const float4*)(cr + c4 * 4);
                acc = fmaf(zp[(size_t)(c4 * 4 + 0) * HWSZ], cv.x, acc);
                acc = fmaf(zp[(size_t)(c4 * 4 + 1) * HWSZ], cv.y, acc);
                acc = fmaf(zp[(size_t)(c4 * 4 + 2) * HWSZ], cv.z, acc);
                acc = fmaf(zp[(size_t)(c4 * 4 + 3) * HWSZ], cv.w, acc);
            }
            float t1 = a + ws[WM_B + kk];
            float d  = t1 - 2.0f * acc;
            if (d < d1) { d1 = d; i1 = kk; }     // j ascending => first-index wins
        }
#pragma unroll
        for (int off = 1; off < 64; off <<= 1) {
            float od = __shfl_xor(d1, off);
            int   oi = __shfl_xor(i1, off);
            bool take = (od < d1) || (od == d1 && oi < i1);
            d1 = take ? od : d1; i1 = take ? oi : i1;
        }
        if (lane == 0) ((int*)ws)[WM_IDX + row] = i1;
    }
}

// ---------- pass3: z_q + idx out + loss partials (verified epilogue, standalone) ----------
__global__ __launch_bounds__(256)
void pass3_k(const float* __restrict__ z, const float* __restrict__ cb,
             float* __restrict__ ws, float* __restrict__ out) {
    __shared__ float es[32 * 256];
    __shared__ int   bi_s[128];
    __shared__ float wred[4];
    const int t = threadIdx.x;
    const int n0 = blockIdx.x * 128;
    const int b = n0 >> 12, hw0 = n0 & 4095;
    const size_t zb = (size_t)b * DIMS * HWSZ;

    if (t < 128) bi_s[t] = ((const int*)ws)[WM_IDX + n0 + t];

    float lpart = 0.0f;
    for (int pass = 0; pass < 4; ++pass) {
        const int tp = pass * 32;
        __syncthreads();
        for (int rr = 0; rr < 32; ++rr) {
            const int idx = bi_s[tp + rr];
            es[rr * 256 + (t ^ rr)] = cb[(size_t)idx * DIMS + t];
        }
        __syncthreads();
#pragma unroll 4
        for (int r2 = 0; r2 < 32; ++r2) {
            const int fl2 = r2 * 256 + t;
            const int c   = fl2 >> 5;
            const int tnl = fl2 & 31;
            const float e = es[tnl * 256 + (c ^ tnl)];
            const size_t gz = zb + (size_t)c * HWSZ + hw0 + tp + tnl;
            const float zv = z[gz];
            const float diff = e - zv;
            lpart = fmaf(diff, diff, lpart);
            out[gz] = zv + diff;
        }
    }
    if (t < 128) out[(size_t)NPOS * DIMS + n0 + t] = (float)bi_s[t];

    for (int off = 32; off > 0; off >>= 1) lpart += __shfl_down(lpart, off);
    if ((t & 63) == 0) wred[t >> 6] = lpart;
    __syncthreads();
    if (t == 0)
        ws[WM_PART + blockIdx.x] = wred[0] + wred[1] + wred[2] + wred[3];
}

__global__ void loss_final_m(const float* __restrict__ ws, float* __restrict__ out) {
    __shared__ float ls[64];
    const int t = threadIdx.x;   // 64 threads
    float s = 0.0f;
    for (int i = 0; i < 8; ++i) s += ws[WM_PART + t * 8 + i];
    ls[t] = s;
    __syncthreads();
    if (t == 0) {
        float tot = 0.0f;
        for (int i = 0; i < 64; ++i) tot += ls[i];
        float m = tot / 16777216.0f;
        out[(size_t)NPOS * DIMS + NPOS] = m + 0.25f * m;
    }
}

// ===================== OLD VERIFIED F32 PATH (fallback) =====================
#define TN 128
#define TK 128
#define CC 16
#define NKC (NCODES / TK)
#define NCC (DIMS / CC)
#define WS_LOSS 0
#define WS_B    256
#define WS_A    2048
#define WS_CBT  67584

__global__ void prep_kernel(const float* __restrict__ cb, float* __restrict__ ws) {
#pragma clang fp contract(off)
    int k = blockIdx.x * blockDim.x + threadIdx.x;
    if (k == 0) ws[WS_LOSS] = 0.0f;
    float* bsum = ws + WS_B;
    float* cbT  = ws + WS_CBT;
    if (k < NCODES) {
        float s = 0.0f;
        for (int c = 0; c < DIMS; ++c) {
            float v = cb[k * DIMS + c];
            float p = v * v;
            s = s + p;
            cbT[c * NCODES + k] = v;
        }
        bsum[k] = s;
    }
}

__global__ void a_kernel(const float* __restrict__ z, float* __restrict__ ws) {
#pragma clang fp contract(off)
    int n = blockIdx.x * blockDim.x + threadIdx.x;
    int b = n >> 12;
    int hw = n & 4095;
    const float* zp = z + (size_t)b * DIMS * HWSZ + hw;
    float s = 0.0f;
    for (int c = 0; c < DIMS; ++c) {
        float v = zp[(size_t)c * HWSZ];
        float p = v * v;
        s = s + p;
    }
    ws[WS_A + n] = s;
}

__global__ __launch_bounds__(256, 4)
void vq_main(const float* __restrict__ z, const float* __restrict__ cb,
             float* __restrict__ ws, float* __restrict__ out) {
    __shared__ __align__(16) char smem[33792];
    float* zs    = (float*)smem;
    float* cbs   = (float*)(smem + 8192);
    float* red_d = (float*)(smem + 16384);
    int*   red_i = (int*)(smem + 24576);
    float* es    = (float*)smem;
    int*   bi_s  = (int*)(smem + 32768);
    float* a_s   = (float*)(smem + 33280);

    const float* bsum = ws + WS_B;
    const float* a_g  = ws + WS_A;
    const float* cbT  = ws + WS_CBT;

    const int t  = threadIdx.x;
    const int ti = t & 15;
    const int tj = t >> 4;

    const int n0  = blockIdx.x * TN;
    const int b   = n0 >> 12;
    const int hw0 = n0 & 4095;
    const size_t zb = (size_t)b * DIMS * HWSZ;

    if (t < TN) a_s[t] = a_g[n0 + t];

    float run_d = 1e30f;
    int   run_i = 0;

    for (int kc = 0; kc < NKC; ++kc) {
        const int k0 = kc * TK;
        float acc[8][8];
#pragma unroll
        for (int i = 0; i < 8; ++i)
#pragma unroll
            for (int j = 0; j < 8; ++j) acc[i][j] = 0.0f;

        for (int ccI = 0; ccI < NCC; ++ccI) {
            const int c0 = ccI * CC;
            __syncthreads();
#pragma unroll
            for (int issue = 0; issue < 2; ++issue) {
                int f   = issue * 1024 + t * 4;
                int cl  = f >> 7;
                int col = f & 127;
                float4 v = *(const float4*)(z + zb + (size_t)(c0 + cl) * HWSZ + hw0 + col);
                *(float4*)(zs + cl * TN + col) = v;
            }
#pragma unroll
            for (int issue = 0; issue < 2; ++issue) {
                int f   = issue * 1024 + t * 4;
                int cl  = f >> 7;
                int col = f & 127;
                float4 v = *(const float4*)(cbT + (size_t)(c0 + cl) * NCODES + k0 + col);
                *(float4*)(cbs + cl * TK + col) = v;
            }
            __syncthreads();
#pragma unroll
            for (int c = 0; c < CC; ++c) {
                const float4 za  = *(const float4*)(zs + c * TN + ti * 4);
                const float4 zb4 = *(const float4*)(zs + c * TN + 64 + ti * 4);
                const float4 ca  = *(const float4*)(cbs + c * TK + tj * 8);
                const float4 cb4 = *(const float4*)(cbs + c * TK + tj * 8 + 4);
                float zr[8] = {za.x, za.y, za.z, za.w, zb4.x, zb4.y, zb4.z, zb4.w};
                float cr[8] = {ca.x, ca.y, ca.z, ca.w, cb4.x, cb4.y, cb4.z, cb4.w};
#pragma unroll
                for (int i = 0; i < 8; ++i)
#pragma unroll
                    for (int j = 0; j < 8; ++j)
                        acc[i][j] = fmaf(zr[i], cr[j], acc[i][j]);
            }
        }

        float bfrag[8];
#pragma unroll
        for (int j = 0; j < 8; ++j) bfrag[j] = bsum[k0 + tj * 8 + j];

        __syncthreads();
#pragma unroll
        for (int i = 0; i < 8; ++i) {
            const int nl = (i < 4) ? (ti * 4 + i) : (64 + ti * 4 + (i - 4));
            const float an = a_s[nl];
            float bd = 1e30f;
            int   bi = 0;
#pragma unroll
            for (int j = 0; j < 8; ++j) {
                const int kk = k0 + tj * 8 + j;
                float t1 = an + bfrag[j];
                float d  = t1 - 2.0f * acc[i][j];
                if (d < bd) { bd = d; bi = kk; }
            }
            red_d[nl * 16 + tj] = bd;
            red_i[nl * 16 + tj] = bi;
        }
        __syncthreads();
        if (t < TN) {
#pragma unroll 4
            for (int tj2 = 0; tj2 < 16; ++tj2) {
                float d2 = red_d[t * 16 + tj2];
                int   i2 = red_i[t * 16 + tj2];
                if (d2 < run_d) { run_d = d2; run_i = i2; }
            }
        }
    }

    if (t < TN) {
        bi_s[t] = run_i;
        out[(size_t)NPOS * DIMS + n0 + t] = (float)run_i;
    }

    float lpart = 0.0f;
    for (int pass = 0; pass < 4; ++pass) {
        const int tp = pass * 32;
        __syncthreads();
        for (int rr = 0; rr < 32; ++rr) {
            const int idx = bi_s[tp + rr];
            es[rr * 256 + (t ^ rr)] = cb[(size_t)idx * DIMS + t];
        }
        __syncthreads();
#pragma unroll 4
        for (int r2 = 0; r2 < 32; ++r2) {
            const int fl2 = r2 * 256 + t;
            const int c   = fl2 >> 5;
            const int tnl = fl2 & 31;
            const float e = es[tnl * 256 + (c ^ tnl)];
            const size_t gz = zb + (size_t)c * HWSZ + hw0 + tp + tnl;
            const float zv = z[gz];
            const float diff = e - zv;
            lpart = fmaf(diff, diff, lpart);
            out[gz] = zv + diff;
        }
    }

    for (int off = 32; off > 0; off >>= 1)
        lpart += __shfl_down(lpart, off);
    if ((t & 63) == 0) a_s[t >> 6] = lpart;
    __syncthreads();
    if (t == 0) {
        float s = a_s[0] + a_s[1] + a_s[2] + a_s[3];
        atomicAdd(ws + WS_LOSS, s);
    }
}

__global__ void loss_final(const float* __restrict__ ws, float* __restrict__ out) {
    float m = ws[WS_LOSS] / 16777216.0f;
    out[(size_t)NPOS * DIMS + NPOS] = m + 0.25f * m;
}

// ===================== launch =====================
extern "C" void kernel_launch(void* const* d_in, const int* in_sizes, int n_in,
                              void* d_out, int out_size, void* d_ws, size_t ws_size,
                              hipStream_t stream) {
    (void)in_sizes; (void)n_in; (void)out_size;
    const float* z  = (const float*)d_in[0];
    const float* cb = (const float*)d_in[1];
    float* ws  = (float*)d_ws;
    float* out = (float*)d_out;

    if (ws_size >= WM_END_BYTES) {
        prep_cb_m<<<4, 256, 0, stream>>>(cb, ws);
        prep_a_m<<<NPOS / 256, 256, 0, stream>>>(z, ws);
        prep_zsplit<<<1024, 256, 0, stream>>>(z, ws);
        vq_mfma_k<<<1024, 256, 0, stream>>>(ws, ws);
        rescue_k<<<256, 256, 0, stream>>>(z, cb, ws);
        pass3_k<<<512, 256, 0, stream>>>(z, cb, ws, out);
        loss_final_m<<<1, 64, 0, stream>>>(ws, out);
    } else {
        prep_kernel<<<4, 256, 0, stream>>>(cb, ws);
        a_kernel<<<NPOS / 256, 256, 0, stream>>>(z, ws);
        vq_main<<<NPOS / TN, 256, 0, stream>>>(z, cb, ws, out);
        loss_final<<<1, 1, 0, stream>>>(ws, out);
    }
}

// Round 9
// 834.750 us; speedup vs baseline: 1.1794x; 1.1794x over previous
//
#include <hip/hip_runtime.h>
#include <hip/hip_bf16.h>

#define NCODES 1024
#define DIMS   256
#define HWSZ   4096
#define NPOS   65536

// ---------------- shared helpers ----------------
__device__ __forceinline__ unsigned short f2bf_rne(float f) {
    unsigned int x = __float_as_uint(f);
    unsigned int r = x + 0x7fffu + ((x >> 16) & 1u);
    return (unsigned short)(r >> 16);
}
__device__ __forceinline__ float bf2f(unsigned short h) {
    return __uint_as_float(((unsigned int)h) << 16);
}
__device__ __forceinline__ void gl_lds16(const void* g, void* l) {
    __builtin_amdgcn_global_load_lds(
        (const __attribute__((address_space(1))) unsigned int*)g,
        (__attribute__((address_space(3))) unsigned int*)l, 16, 0, 0);
}

typedef short bf16x8v __attribute__((ext_vector_type(8)));
typedef float f32x4  __attribute__((ext_vector_type(4)));

// ================= MFMA PATH ws layout (float words) =================
#define WM_CNT   0
#define WM_PART  64        // 512 block partials (pass3)
#define WM_B     1024      // 1024 exact ||e||^2
#define WM_A     2048      // 65536 exact ||z||^2
#define WM_IDX   67584     // 65536 int
#define WM_LIST  133120    // 65536 int
#define WM_BM    198656    // B bf16 frag-tiled: 1024x768 = 786432 bf16 = 393216 words
#define WM_AM    591872    // A bf16 frag-tiled: 65536x512 = 16777216 words
#define WM_END_BYTES 69476352ull
#define THRESH 2.5e-4f

// ---------- prep_cb_m: exact b_k + B_mem bf16 frag-tiled [kc][ci][cg][q][c16][8] ----------
__global__ void prep_cb_m(const float* __restrict__ cb, float* __restrict__ ws) {
#pragma clang fp contract(off)
    int k = blockIdx.x * 256 + threadIdx.x;   // 0..1023
    if (k == 0) ((int*)ws)[WM_CNT] = 0;
    float s = 0.0f;
    for (int c = 0; c < DIMS; ++c) {
        float v = cb[k * DIMS + c];
        float p = v * v;
        s = s + p;
    }
    ws[WM_B + k] = s;

    unsigned short* Bm = (unsigned short*)(ws + WM_BM);
    const int kc = k >> 8, cg = (k >> 4) & 15, c16 = k & 15;
    for (int ci = 0; ci < 24; ++ci) {
        const int base = (ci < 8 ? ci : (ci < 16 ? ci - 8 : ci - 16)) * 32;
        const bool lo = (ci >= 8 && ci < 16);
        for (int q = 0; q < 4; ++q) {
            union { unsigned short u[8]; uint4 v4; } pk;
#pragma unroll
            for (int j = 0; j < 8; ++j) {
                float v = cb[k * DIMS + base + q * 8 + j];
                unsigned short h = f2bf_rne(v);
                if (lo) h = f2bf_rne(v - bf2f(h));
                pk.u[j] = h;
            }
            size_t off = ((size_t)(((kc * 24 + ci) * 16 + cg) * 4 + q)) * 128 + c16 * 8;
            *(uint4*)(Bm + off) = pk.v4;
        }
    }
}

// ---------- prep_a_m: exact a_n (identical math to verified a_kernel) ----------
__global__ void prep_a_m(const float* __restrict__ z, float* __restrict__ ws) {
#pragma clang fp contract(off)
    int n = blockIdx.x * blockDim.x + threadIdx.x;
    int b = n >> 12;
    int hw = n & 4095;
    const float* zp = z + (size_t)b * DIMS * HWSZ + hw;
    float s = 0.0f;
    for (int c = 0; c < DIMS; ++c) {
        float v = zp[(size_t)c * HWSZ];
        float p = v * v;
        s = s + p;
    }
    ws[WM_A + n] = s;
}

// ---------- prep_zsplit: z -> A_mem frag-tiled [tile][kp16][g*4+q][p16][8] ----------
__global__ __launch_bounds__(256)
void prep_zsplit(const float* __restrict__ z, float* __restrict__ ws) {
    __shared__ float lz[128 * 64];   // 32 KB half-tile [c_local][p]
    unsigned short* Am = (unsigned short*)(ws + WM_AM);
    const int t = threadIdx.x;
    const int tile = blockIdx.x;            // 0..1023
    const int n0 = tile * 64;
    const int b = n0 >> 12, hw0 = n0 & 4095;
    const size_t zbase = (size_t)b * DIMS * HWSZ + hw0;
    const int p = t & 63, grp = t >> 6;
    unsigned short* At = Am + (size_t)tile * 32768;   // 65536 B = 32768 bf16

    for (int half = 0; half < 2; ++half) {
        const int coff = half * 128;
        __syncthreads();
        for (int rep = 0; rep < 32; ++rep) {
            int cl = rep * 4 + grp;
            lz[cl * 64 + p] = z[zbase + (size_t)(coff + cl) * HWSZ + p];
        }
        __syncthreads();
        for (int run = 0; run < 4; ++run) {
            const int c0l = grp * 32 + run * 8;
            union { unsigned short u[8]; uint4 v4; } hh, ll;
#pragma unroll
            for (int j = 0; j < 8; ++j) {
                float v = lz[(c0l + j) * 64 + p];
                unsigned short h = f2bf_rne(v);
                hh.u[j] = h;
                ll.u[j] = f2bf_rne(v - bf2f(h));
            }
            const int kp = (coff >> 5) + grp;     // 0..3 / 4..7
            const size_t byteH = (size_t)kp * 4096 +
                                 (size_t)((p >> 4) * 4 + run) * 256 + (p & 15) * 16;
            *(uint4*)((char*)At + byteH)         = hh.v4;
            *(uint4*)((char*)At + byteH + 32768) = ll.v4;   // kp+8 (zl)
        }
    }
}

// ---------- vq_mfma_k: 64 pos x 1024 codes per block, K=768 split-contraction ----------
__global__ __launch_bounds__(256, 4)
void vq_mfma_k(const float* __restrict__ ws_ro, float* __restrict__ ws) {
    __shared__ char Al[4096];
    __shared__ char Bl[16384];
    __shared__ float rd1[256], rd2[256];
    __shared__ int   ri[256];

    const int t = threadIdx.x, w = t >> 6, lane = t & 63;
    const int rg = lane >> 4, cl = lane & 15;
    const int tile = blockIdx.x, n0 = tile * 64;

    const unsigned short* Am = (const unsigned short*)(ws_ro + WM_AM);
    const unsigned short* Bm = (const unsigned short*)(ws_ro + WM_BM);
    const float* bsum = ws_ro + WM_B;
    const char* Atile = (const char*)(Am + (size_t)tile * 32768);

    rd1[t] = 1e30f; rd2[t] = 1e30f; ri[t] = 0;

    for (int kc = 0; kc < 4; ++kc) {
        f32x4 acc[4][4];
#pragma unroll
        for (int g = 0; g < 4; ++g)
#pragma unroll
            for (int bb = 0; bb < 4; ++bb)
#pragma unroll
                for (int r = 0; r < 4; ++r) acc[g][bb][r] = 0.0f;

        for (int ci = 0; ci < 24; ++ci) {
            __syncthreads();
            const int kp = (ci < 8) ? ci : ci - 8;
            gl_lds16(Atile + (size_t)kp * 4096 + t * 16, Al + (t & ~63) * 16);
            const char* Bci = (const char*)Bm + (size_t)(kc * 24 + ci) * 16384;
#pragma unroll
            for (int i = 0; i < 4; ++i)
                gl_lds16(Bci + (size_t)(i * 256 + t) * 16,
                         Bl + i * 4096 + (t & ~63) * 16);
            __syncthreads();

            bf16x8v af[4], bfv[4];
#pragma unroll
            for (int g = 0; g < 4; ++g)
                af[g] = *(const bf16x8v*)(Al + (g * 4 + rg) * 256 + cl * 16);
#pragma unroll
            for (int bb = 0; bb < 4; ++bb)
                bfv[bb] = *(const bf16x8v*)(Bl + ((w * 4 + bb) * 4 + rg) * 256 + cl * 16);
#pragma unroll
            for (int g = 0; g < 4; ++g)
#pragma unroll
                for (int bb = 0; bb < 4; ++bb)
                    acc[g][bb] = __builtin_amdgcn_mfma_f32_16x16x32_bf16(
                        af[g], bfv[bb], acc[g][bb], 0, 0, 0);
        }

        // per-kc argmin epilogue (approx s = b_k - 2*dot; a_n drops out of argmin)
        const int cwbase = kc * 256 + w * 64;
        float bs[4];
#pragma unroll
        for (int bb = 0; bb < 4; ++bb) bs[bb] = bsum[cwbase + bb * 16 + cl];

#pragma unroll
        for (int g = 0; g < 4; ++g) {
#pragma unroll
            for (int r = 0; r < 4; ++r) {
                float d1 = 1e30f, d2 = 1e30f; int i1 = 0;
#pragma unroll
                for (int bb = 0; bb < 4; ++bb) {
                    float s = fmaf(-2.0f, acc[g][bb][r], bs[bb]);
                    int kk = cwbase + bb * 16 + cl;
                    if (s < d1) { d2 = d1; d1 = s; i1 = kk; }
                    else if (s < d2) d2 = s;
                }
#pragma unroll
                for (int off = 1; off < 16; off <<= 1) {
                    float o1 = __shfl_xor(d1, off);
                    float o2 = __shfl_xor(d2, off);
                    int   oi = __shfl_xor(i1, off);
                    float nm = fminf(fmaxf(d1, o1), fminf(d2, o2));
                    bool take = (o1 < d1) || (o1 == d1 && oi < i1);
                    d1 = take ? o1 : d1; i1 = take ? oi : i1; d2 = nm;
                }
                if (cl == 0) {
                    int slot = w * 64 + g * 16 + rg * 4 + r;
                    float o1 = rd1[slot], o2 = rd2[slot];
                    if (d1 < o1) { ri[slot] = i1; rd1[slot] = d1; rd2[slot] = fminf(o1, d2); }
                    else          rd2[slot] = fminf(o2, d1);
                }
            }
        }
    }

    __syncthreads();
    if (t < 64) {
        float d1 = rd1[t], d2 = rd2[t]; int i1 = ri[t];
#pragma unroll
        for (int ww = 1; ww < 4; ++ww) {
            float o1 = rd1[ww * 64 + t], o2 = rd2[ww * 64 + t];
            int   oi = ri[ww * 64 + t];
            if (o1 < d1) { d2 = fminf(d1, o2); d1 = o1; i1 = oi; }
            else          d2 = fminf(d2, o1);
        }
        ((int*)ws)[WM_IDX + n0 + t] = i1;
        if (d2 - d1 < THRESH) {
            int slot = atomicAdd((int*)ws + WM_CNT, 1);
            ((int*)ws)[WM_LIST + slot] = n0 + t;
        }
    }
}

// ---------- rescue: exact f32 re-solve of flagged rows ----------
// Rewritten R8: one wave per row; z-row staged once in registers and
// broadcast via __shfl; 16 codes/lane as 16 independent fmaf chains
// streaming contiguous cb rows as float4 (L2-resident, 1 MB total).
// Accumulation order per code is c = 0..255 ascending fmaf — identical
// formula/order/tie-break semantics to the previous rescue.
__global__ __launch_bounds__(256)
void rescue_k(const float* __restrict__ z, const float* __restrict__ cb,
              float* __restrict__ ws) {
#pragma clang fp contract(off)
    const int t = threadIdx.x, lane = t & 63;
    const int gwave = blockIdx.x * 4 + (t >> 6);     // 0..4095
    const int cnt = ((const int*)ws)[WM_CNT];
    for (int i = gwave; i < cnt; i += 4096) {
        const int row = ((const int*)ws)[WM_LIST + i];
        const int b = row >> 12, hw = row & 4095;
        const float* zp = z + (size_t)b * DIMS * HWSZ + hw;
        // stage z-row: lane holds c = q*64+lane, q=0..3 (4 scattered loads total)
        float zq0 = zp[(size_t)lane * HWSZ];
        float zq1 = zp[(size_t)(64 + lane) * HWSZ];
        float zq2 = zp[(size_t)(128 + lane) * HWSZ];
        float zq3 = zp[(size_t)(192 + lane) * HWSZ];

        float acc[16];
#pragma unroll
        for (int j = 0; j < 16; ++j) acc[j] = 0.0f;
        const float* crb = cb + (size_t)(lane * 16) * DIMS;   // lane's 16 codes

#pragma unroll
        for (int q = 0; q < 4; ++q) {
            const float zsrc = (q == 0) ? zq0 : (q == 1) ? zq1 : (q == 2) ? zq2 : zq3;
            for (int c4 = 0; c4 < 16; ++c4) {      // c = q*64 + c4*4 + {0..3}
                const int cbase = q * 64 + c4 * 4;
                const float z0 = __shfl(zsrc, c4 * 4 + 0);
                const float z1 = __shfl(zsrc, c4 * 4 + 1);
                const float z2 = __shfl(zsrc, c4 * 4 + 2);
                const float z3 = __shfl(zsrc, c4 * 4 + 3);
#pragma unroll
                for (int j = 0; j < 16; ++j) {
                    const float4 cv = *(const float4*)(crb + (size_t)j * DIMS + cbase);
                    acc[j] = fmaf(z0, cv.x, acc[j]);
                    acc[j] = fmaf(z1, cv.y, acc[j]);
                    acc[j] = fmaf(z2, cv.z, acc[j]);
                    acc[j] = fmaf(z3, cv.w, acc[j]);
                }
            }
        }

        const float a = ws[WM_A + row];
        float d1 = 1e30f; int i1 = 0;
#pragma unroll
        for (int j = 0; j < 16; ++j) {             // j ascending => first-index wins
            const int kk = lane * 16 + j;
            float t1 = a + ws[WM_B + kk];
            float d  = t1 - 2.0f * acc[j];
            if (d < d1) { d1 = d; i1 = kk; }
        }
#pragma unroll
        for (int off = 1; off < 64; off <<= 1) {
            float od = __shfl_xor(d1, off);
            int   oi = __shfl_xor(i1, off);
            bool take = (od < d1) || (od == d1 && oi < i1);
            d1 = take ? od : d1; i1 = take ? oi : i1;
        }
        if (lane == 0) ((int*)ws)[WM_IDX + row] = i1;
    }
}

// ---------- pass3: z_q + idx out + loss partials (verified epilogue, standalone) ----------
__global__ __launch_bounds__(256)
void pass3_k(const float* __restrict__ z, const float* __restrict__ cb,
             float* __restrict__ ws, float* __restrict__ out) {
    __shared__ float es[32 * 256];
    __shared__ int   bi_s[128];
    __shared__ float wred[4];
    const int t = threadIdx.x;
    const int n0 = blockIdx.x * 128;
    const int b = n0 >> 12, hw0 = n0 & 4095;
    const size_t zb = (size_t)b * DIMS * HWSZ;

    if (t < 128) bi_s[t] = ((const int*)ws)[WM_IDX + n0 + t];

    float lpart = 0.0f;
    for (int pass = 0; pass < 4; ++pass) {
        const int tp = pass * 32;
        __syncthreads();
        for (int rr = 0; rr < 32; ++rr) {
            const int idx = bi_s[tp + rr];
            es[rr * 256 + (t ^ rr)] = cb[(size_t)idx * DIMS + t];
        }
        __syncthreads();
#pragma unroll 4
        for (int r2 = 0; r2 < 32; ++r2) {
            const int fl2 = r2 * 256 + t;
            const int c   = fl2 >> 5;
            const int tnl = fl2 & 31;
            const float e = es[tnl * 256 + (c ^ tnl)];
            const size_t gz = zb + (size_t)c * HWSZ + hw0 + tp + tnl;
            const float zv = z[gz];
            const float diff = e - zv;
            lpart = fmaf(diff, diff, lpart);
            out[gz] = zv + diff;
        }
    }
    if (t < 128) out[(size_t)NPOS * DIMS + n0 + t] = (float)bi_s[t];

    for (int off = 32; off > 0; off >>= 1) lpart += __shfl_down(lpart, off);
    if ((t & 63) == 0) wred[t >> 6] = lpart;
    __syncthreads();
    if (t == 0)
        ws[WM_PART + blockIdx.x] = wred[0] + wred[1] + wred[2] + wred[3];
}

__global__ void loss_final_m(const float* __restrict__ ws, float* __restrict__ out) {
    __shared__ float ls[64];
    const int t = threadIdx.x;   // 64 threads
    float s = 0.0f;
    for (int i = 0; i < 8; ++i) s += ws[WM_PART + t * 8 + i];
    ls[t] = s;
    __syncthreads();
    if (t == 0) {
        float tot = 0.0f;
        for (int i = 0; i < 64; ++i) tot += ls[i];
        float m = tot / 16777216.0f;
        out[(size_t)NPOS * DIMS + NPOS] = m + 0.25f * m;
    }
}

// ===================== OLD VERIFIED F32 PATH (fallback) =====================
#define TN 128
#define TK 128
#define CC 16
#define NKC (NCODES / TK)
#define NCC (DIMS / CC)
#define WS_LOSS 0
#define WS_B    256
#define WS_A    2048
#define WS_CBT  67584

__global__ void prep_kernel(const float* __restrict__ cb, float* __restrict__ ws) {
#pragma clang fp contract(off)
    int k = blockIdx.x * blockDim.x + threadIdx.x;
    if (k == 0) ws[WS_LOSS] = 0.0f;
    float* bsum = ws + WS_B;
    float* cbT  = ws + WS_CBT;
    if (k < NCODES) {
        float s = 0.0f;
        for (int c = 0; c < DIMS; ++c) {
            float v = cb[k * DIMS + c];
            float p = v * v;
            s = s + p;
            cbT[c * NCODES + k] = v;
        }
        bsum[k] = s;
    }
}

__global__ void a_kernel(const float* __restrict__ z, float* __restrict__ ws) {
#pragma clang fp contract(off)
    int n = blockIdx.x * blockDim.x + threadIdx.x;
    int b = n >> 12;
    int hw = n & 4095;
    const float* zp = z + (size_t)b * DIMS * HWSZ + hw;
    float s = 0.0f;
    for (int c = 0; c < DIMS; ++c) {
        float v = zp[(size_t)c * HWSZ];
        float p = v * v;
        s = s + p;
    }
    ws[WS_A + n] = s;
}

__global__ __launch_bounds__(256, 4)
void vq_main(const float* __restrict__ z, const float* __restrict__ cb,
             float* __restrict__ ws, float* __restrict__ out) {
    __shared__ __align__(16) char smem[33792];
    float* zs    = (float*)smem;
    float* cbs   = (float*)(smem + 8192);
    float* red_d = (float*)(smem + 16384);
    int*   red_i = (int*)(smem + 24576);
    float* es    = (float*)smem;
    int*   bi_s  = (int*)(smem + 32768);
    float* a_s   = (float*)(smem + 33280);

    const float* bsum = ws + WS_B;
    const float* a_g  = ws + WS_A;
    const float* cbT  = ws + WS_CBT;

    const int t  = threadIdx.x;
    const int ti = t & 15;
    const int tj = t >> 4;

    const int n0  = blockIdx.x * TN;
    const int b   = n0 >> 12;
    const int hw0 = n0 & 4095;
    const size_t zb = (size_t)b * DIMS * HWSZ;

    if (t < TN) a_s[t] = a_g[n0 + t];

    float run_d = 1e30f;
    int   run_i = 0;

    for (int kc = 0; kc < NKC; ++kc) {
        const int k0 = kc * TK;
        float acc[8][8];
#pragma unroll
        for (int i = 0; i < 8; ++i)
#pragma unroll
            for (int j = 0; j < 8; ++j) acc[i][j] = 0.0f;

        for (int ccI = 0; ccI < NCC; ++ccI) {
            const int c0 = ccI * CC;
            __syncthreads();
#pragma unroll
            for (int issue = 0; issue < 2; ++issue) {
                int f   = issue * 1024 + t * 4;
                int cl  = f >> 7;
                int col = f & 127;
                float4 v = *(const float4*)(z + zb + (size_t)(c0 + cl) * HWSZ + hw0 + col);
                *(float4*)(zs + cl * TN + col) = v;
            }
#pragma unroll
            for (int issue = 0; issue < 2; ++issue) {
                int f   = issue * 1024 + t * 4;
                int cl  = f >> 7;
                int col = f & 127;
                float4 v = *(const float4*)(cbT + (size_t)(c0 + cl) * NCODES + k0 + col);
                *(float4*)(cbs + cl * TK + col) = v;
            }
            __syncthreads();
#pragma unroll
            for (int c = 0; c < CC; ++c) {
                const float4 za  = *(const float4*)(zs + c * TN + ti * 4);
                const float4 zb4 = *(const float4*)(zs + c * TN + 64 + ti * 4);
                const float4 ca  = *(const float4*)(cbs + c * TK + tj * 8);
                const float4 cb4 = *(const float4*)(cbs + c * TK + tj * 8 + 4);
                float zr[8] = {za.x, za.y, za.z, za.w, zb4.x, zb4.y, zb4.z, zb4.w};
                float cr[8] = {ca.x, ca.y, ca.z, ca.w, cb4.x, cb4.y, cb4.z, cb4.w};
#pragma unroll
                for (int i = 0; i < 8; ++i)
#pragma unroll
                    for (int j = 0; j < 8; ++j)
                        acc[i][j] = fmaf(zr[i], cr[j], acc[i][j]);
            }
        }

        float bfrag[8];
#pragma unroll
        for (int j = 0; j < 8; ++j) bfrag[j] = bsum[k0 + tj * 8 + j];

        __syncthreads();
#pragma unroll
        for (int i = 0; i < 8; ++i) {
            const int nl = (i < 4) ? (ti * 4 + i) : (64 + ti * 4 + (i - 4));
            const float an = a_s[nl];
            float bd = 1e30f;
            int   bi = 0;
#pragma unroll
            for (int j = 0; j < 8; ++j) {
                const int kk = k0 + tj * 8 + j;
                float t1 = an + bfrag[j];
                float d  = t1 - 2.0f * acc[i][j];
                if (d < bd) { bd = d; bi = kk; }
            }
            red_d[nl * 16 + tj] = bd;
            red_i[nl * 16 + tj] = bi;
        }
        __syncthreads();
        if (t < TN) {
#pragma unroll 4
            for (int tj2 = 0; tj2 < 16; ++tj2) {
                float d2 = red_d[t * 16 + tj2];
                int   i2 = red_i[t * 16 + tj2];
                if (d2 < run_d) { run_d = d2; run_i = i2; }
            }
        }
    }

    if (t < TN) {
        bi_s[t] = run_i;
        out[(size_t)NPOS * DIMS + n0 + t] = (float)run_i;
    }

    float lpart = 0.0f;
    for (int pass = 0; pass < 4; ++pass) {
        const int tp = pass * 32;
        __syncthreads();
        for (int rr = 0; rr < 32; ++rr) {
            const int idx = bi_s[tp + rr];
            es[rr * 256 + (t ^ rr)] = cb[(size_t)idx * DIMS + t];
        }
        __syncthreads();
#pragma unroll 4
        for (int r2 = 0; r2 < 32; ++r2) {
            const int fl2 = r2 * 256 + t;
            const int c   = fl2 >> 5;
            const int tnl = fl2 & 31;
            const float e = es[tnl * 256 + (c ^ tnl)];
            const size_t gz = zb + (size_t)c * HWSZ + hw0 + tp + tnl;
            const float zv = z[gz];
            const float diff = e - zv;
            lpart = fmaf(diff, diff, lpart);
            out[gz] = zv + diff;
        }
    }

    for (int off = 32; off > 0; off >>= 1)
        lpart += __shfl_down(lpart, off);
    if ((t & 63) == 0) a_s[t >> 6] = lpart;
    __syncthreads();
    if (t == 0) {
        float s = a_s[0] + a_s[1] + a_s[2] + a_s[3];
        atomicAdd(ws + WS_LOSS, s);
    }
}

__global__ void loss_final(const float* __restrict__ ws, float* __restrict__ out) {
    float m = ws[WS_LOSS] / 16777216.0f;
    out[(size_t)NPOS * DIMS + NPOS] = m + 0.25f * m;
}

// ===================== launch =====================
extern "C" void kernel_launch(void* const* d_in, const int* in_sizes, int n_in,
                              void* d_out, int out_size, void* d_ws, size_t ws_size,
                              hipStream_t stream) {
    (void)in_sizes; (void)n_in; (void)out_size;
    const float* z  = (const float*)d_in[0];
    const float* cb = (const float*)d_in[1];
    float* ws  = (float*)d_ws;
    float* out = (float*)d_out;

    if (ws_size >= WM_END_BYTES) {
        prep_cb_m<<<4, 256, 0, stream>>>(cb, ws);
        prep_a_m<<<NPOS / 256, 256, 0, stream>>>(z, ws);
        prep_zsplit<<<1024, 256, 0, stream>>>(z, ws);
        vq_mfma_k<<<1024, 256, 0, stream>>>(ws, ws);
        rescue_k<<<1024, 256, 0, stream>>>(z, cb, ws);
        pass3_k<<<512, 256, 0, stream>>>(z, cb, ws, out);
        loss_final_m<<<1, 64, 0, stream>>>(ws, out);
    } else {
        prep_kernel<<<4, 256, 0, stream>>>(cb, ws);
        a_kernel<<<NPOS / 256, 256, 0, stream>>>(z, ws);
        vq_main<<<NPOS / TN, 256, 0, stream>>>(z, cb, ws, out);
        loss_final<<<1, 1, 0, stream>>>(ws, out);
    }
}